// Round 12
// baseline (3933.651 us; speedup 1.0000x reference)
//
#include <hip/hip_runtime.h>
#include <hip/hip_bf16.h>
#include <stdint.h>

// GRU-style recurrence, B=64 S=512 D=768 H=1024.
//  prep:  cast x->bf16; Wcat_u bf16 [3072,1024]; WmT bf16; Wh bf16; ccat = W*_u@bm + b*;
//         pack recurrent weights (W*[:,1024:]) into per-block MFMA B-fragments (r,z,i).
//  fold:  Mcat[3072,768] = Wcat_u @ WmT^T           (NT bf16 MFMA GEMM)
//  big:   Gcat[32768,3072] = xbf @ Mcat^T + ccat    (NT bf16 MFMA GEMM, bf16 out)
//  h0:    hf[64,1024] = x[:,0,:] @ Whbf^T + bh
//  rec v12 = SINGLE-CHAIN consolidation (was 4 chains of 64 blocks):
//   64 blocks, each owns cols 16j..16j+15 for ALL 64 batch rows (4 row-tiles).
//   - one dependence chain (no max-over-4-chains jitter), flag lines /4,
//     poll-issuing blocks /4 -> less L3 congestion on the hot sync lines.
//   - all 4 waves run epilogues in parallel (wave w owns row-tile w).
//   - per-wave frag loads: 2-deep vmcnt-counted pipeline over 4 row-tiles;
//     ALL loads in the counted region are inline-asm volatile (exact counts);
//     Gcat prefetch is asm too, issued pre-poll (poll's vmcnt(0) drains it
//     conservatively -- absorbed into poll wait, off the critical path).
//   Exchange (proven R9/R10): packed blocks, atomic_swap_x2 producer stores
//   (L3-resident), sc0sc1 consumer loads, 64B-padded per-producer flags,
//   per-wave sliced gating, lgkm-only barriers.

#define B_  64
#define S_  512
#define D_  768
#define H_  1024

typedef __attribute__((ext_vector_type(8))) short short8;
typedef __attribute__((ext_vector_type(4))) float f32x4;
typedef __attribute__((ext_vector_type(4))) unsigned short u16x4;

static __device__ __forceinline__ short f2bf(float f) {
  union { float f; uint32_t u; } v; v.f = f;
  uint32_t u = v.u;
  u += 0x7FFFu + ((u >> 16) & 1u);   // RNE
  return (short)(u >> 16);
}
static __device__ __forceinline__ float bf2f(short s) {
  union { uint32_t u; float f; } v; v.u = ((uint32_t)(uint16_t)s) << 16;
  return v.f;
}
static __device__ __forceinline__ void load_lds16(const void* g, void* l) {
  __builtin_amdgcn_global_load_lds((const __attribute__((address_space(1))) void*)g,
                                   (__attribute__((address_space(3))) void*)l, 16, 0, 0);
}

// ---- exchange primitives ----
static __device__ __forceinline__ void atomic_store64(void* p, uint64_t v) {
  asm volatile("global_atomic_swap_x2 %0, %1, off" :: "v"(p), "v"(v) : "memory");
}
static __device__ __forceinline__ void atomic_store32(uint32_t* p, uint32_t v) {
  asm volatile("global_atomic_swap %0, %1, off" :: "v"(p), "v"(v) : "memory");
}
static __device__ __forceinline__ u16x4 load_g8(const unsigned short* p) {
  u16x4 v;
  asm volatile("global_load_dwordx2 %0, %1, off" : "=v"(v) : "v"(p));
  return v;
}
static __device__ __forceinline__ void wait_vm0() {
  asm volatile("s_waitcnt vmcnt(0)" ::: "memory");
  __builtin_amdgcn_sched_barrier(0);   // rule 18
}
// LDS-only barrier: orders red[] without draining in-flight vmem
static __device__ __forceinline__ void barrier_lds() {
  asm volatile("s_waitcnt lgkmcnt(0)" ::: "memory");
  __builtin_amdgcn_s_barrier();
  __builtin_amdgcn_sched_barrier(0);
}
// wave polls the 16 line-padded flags of its k-quarter producer slice (R10 form)
static __device__ __forceinline__ void poll16(const uint32_t* base, uint32_t target) {
  const uint32_t* addr = base + ((threadIdx.x & 15) << 4);   // 64B-strided flags
  for (;;) {
    uint32_t v;
    asm volatile("global_load_dword %0, %1, off sc0 sc1\n\ts_waitcnt vmcnt(0)"
                 : "=v"(v) : "v"(addr) : "memory");
    if (__all((int)(v >= target))) break;
  }
  __builtin_amdgcn_sched_barrier(0);
}

// issue 8 frag loads (one row-tile, this wave's k-quarter) -- counted region
#define ISSUE8(buf, src, eoff)                                                    \
  _Pragma("unroll")                                                               \
  for (int t8_ = 0; t8_ < 8; ++t8_)                                               \
    asm volatile("global_load_dwordx4 %0, %1, off sc0 sc1"                        \
                 : "=v"(buf[t8_]) : "v"((src) + (eoff) + t8_ * 2048));

#define WAITV(n)                                                                  \
  asm volatile("s_waitcnt vmcnt(" #n ")" ::: "memory");                           \
  __builtin_amdgcn_sched_barrier(0);

#define MFMA_RZ(buf, ar, az)                                                      \
  _Pragma("unroll")                                                               \
  for (int t8_ = 0; t8_ < 8; ++t8_) {                                             \
    ar = __builtin_amdgcn_mfma_f32_16x16x32_bf16(buf[t8_], wr[t8_], ar, 0, 0, 0); \
    az = __builtin_amdgcn_mfma_f32_16x16x32_bf16(buf[t8_], wz[t8_], az, 0, 0, 0); \
  }

#define MFMA_I(buf, ai)                                                           \
  _Pragma("unroll")                                                               \
  for (int t8_ = 0; t8_ < 8; ++t8_)                                               \
    ai = __builtin_amdgcn_mfma_f32_16x16x32_bf16(buf[t8_], wi[t8_], ai, 0, 0, 0);

// ---------------- prep kernels ----------------

__global__ void cast_f32_bf16_kernel(const float* __restrict__ in, short* __restrict__ out, int n8) {
  int i = blockIdx.x * blockDim.x + threadIdx.x;
  int stride = gridDim.x * blockDim.x;
  for (; i < n8; i += stride) {
    const f32x4* p = (const f32x4*)(in + (size_t)i * 8);
    f32x4 a = p[0], b = p[1];
    short8 o;
    o[0] = f2bf(a[0]); o[1] = f2bf(a[1]); o[2] = f2bf(a[2]); o[3] = f2bf(a[3]);
    o[4] = f2bf(b[0]); o[5] = f2bf(b[1]); o[6] = f2bf(b[2]); o[7] = f2bf(b[3]);
    *(short8*)(out + (size_t)i * 8) = o;
  }
}

// h0 -> packed exchange layout hp[j*1024 + row*16 + col] = h0[row][16j+col], row 0..63
__global__ void pack_h0_kernel(const float* __restrict__ hf, short* __restrict__ hp) {
  int i = blockIdx.x * blockDim.x + threadIdx.x;   // 65536
  int col = i & 15, row = (i >> 4) & 63, j = i >> 10;
  hp[i] = f2bf(hf[(size_t)row * 1024 + j * 16 + col]);
}

// Wcat_u bf16 [3072][1024]: rows 0..1023 = Wz[:, :1024], then Wr, then Wi
__global__ void build_wcat_kernel(const float* __restrict__ Wz, const float* __restrict__ Wr,
                                  const float* __restrict__ Wi, short* __restrict__ out) {
  int idx = blockIdx.x * blockDim.x + threadIdx.x;   // 3072*128
  int n = idx >> 7;
  int k8 = (idx & 127) << 3;
  const float* src;
  if (n < 1024)       src = Wz + ((size_t)n << 11);
  else if (n < 2048)  src = Wr + ((size_t)(n - 1024) << 11);
  else                src = Wi + ((size_t)(n - 2048) << 11);
  const f32x4* p = (const f32x4*)(src + k8);
  f32x4 a = p[0], b = p[1];
  short8 o;
  o[0] = f2bf(a[0]); o[1] = f2bf(a[1]); o[2] = f2bf(a[2]); o[3] = f2bf(a[3]);
  o[4] = f2bf(b[0]); o[5] = f2bf(b[1]); o[6] = f2bf(b[2]); o[7] = f2bf(b[3]);
  *(short8*)(out + ((size_t)n << 10) + k8) = o;
}

// WmT bf16 [768][1024], WmT[d][u] = Wm[u][d]
__global__ void transpose_cast_kernel(const float* __restrict__ in, short* __restrict__ out) {
  __shared__ float tile[32][33];
  int x = (blockIdx.x << 5) + threadIdx.x;    // d, grid.x = 24
  int y0 = (blockIdx.y << 5);                 // u, grid.y = 32
#pragma unroll
  for (int i = threadIdx.y; i < 32; i += 8)
    tile[i][threadIdx.x] = in[(size_t)(y0 + i) * 768 + x];
  __syncthreads();
  int ox = (blockIdx.y << 5) + threadIdx.x;
  int oy0 = (blockIdx.x << 5);
#pragma unroll
  for (int i = threadIdx.y; i < 32; i += 8)
    out[(size_t)(oy0 + i) * 1024 + ox] = f2bf(tile[threadIdx.x][i]);
}

// ccat[n] = sum_k W*[n_local, k<1024] * bm[k] + b*[n_local]
__global__ void ccat_kernel(const float* __restrict__ Wz, const float* __restrict__ Wr,
                            const float* __restrict__ Wi, const float* __restrict__ bm,
                            const float* __restrict__ bz, const float* __restrict__ br,
                            const float* __restrict__ bi, float* __restrict__ ccat) {
  int w = (blockIdx.x * blockDim.x + threadIdx.x) >> 6;
  int lane = threadIdx.x & 63;
  if (w >= 3072) return;
  const float* src; const float* bsrc; int ln;
  if (w < 1024)      { src = Wz + ((size_t)w << 11);          bsrc = bz; ln = w; }
  else if (w < 2048) { src = Wr + ((size_t)(w - 1024) << 11); bsrc = br; ln = w - 1024; }
  else               { src = Wi + ((size_t)(w - 2048) << 11); bsrc = bi; ln = w - 2048; }
  float acc = 0.f;
  for (int k = lane; k < 1024; k += 64) acc += src[k] * bm[k];
  for (int off = 32; off > 0; off >>= 1) acc += __shfl_down(acc, off, 64);
  if (lane == 0) ccat[w] = acc + bsrc[ln];
}

// pack recurrent weights: idx = (((m*64 + j)*4 + w)*8 + t8)*64 + lane, m: 0=r 1=z 2=i
// value = W_m[16j + (lane&15)][1024 + 256w + 32*t8 + 8*(lane>>4) + e]
__global__ void pack_w_kernel(const float* __restrict__ Wz, const float* __restrict__ Wr,
                              const float* __restrict__ Wi, short* __restrict__ out) {
  int idx = blockIdx.x * blockDim.x + threadIdx.x;   // 393216
  int lane = idx & 63;
  int t8 = (idx >> 6) & 7;
  int w = (idx >> 9) & 3;
  int j = (idx >> 11) & 63;
  int m = idx >> 17;
  int colv = (j << 4) + (lane & 15);
  int k = 1024 + (w << 8) + (t8 << 5) + ((lane >> 4) << 3);
  const float* W = (m == 0) ? Wr : (m == 1) ? Wz : Wi;
  const float* p = W + ((size_t)colv << 11) + k;
  short8 o;
#pragma unroll
  for (int e = 0; e < 8; ++e) o[e] = f2bf(p[e]);
  *(short8*)(out + ((size_t)idx << 3)) = o;
}

// ---------------- NT bf16 MFMA GEMM: C[M,N] = A[M,K] @ Bm[N,K]^T (+bias[col]) ----------------

template<bool OUT_F32>
__launch_bounds__(256, 2)
__global__ void gemm_nt_kernel(const short* __restrict__ A, long lda,
                               const short* __restrict__ Bm,
                               void* __restrict__ Cv, int ldc,
                               const float* __restrict__ bias,
                               int M, int N, int K) {
  __shared__ short ldsA[128 * 64];
  __shared__ short ldsB[128 * 64];
  const int tile_m = blockIdx.x << 7;
  const int tile_n = blockIdx.y << 7;
  const int tid = threadIdx.x;
  const int wave = tid >> 6;
  const int lane = tid & 63;
  const int wm = wave & 1;
  const int wn = wave >> 1;
  const int lrow = lane & 15;
  const int lgrp = lane >> 4;

  f32x4 acc[4][4];
#pragma unroll
  for (int a = 0; a < 4; ++a)
#pragma unroll
    for (int b = 0; b < 4; ++b) acc[a][b] = (f32x4){0.f, 0.f, 0.f, 0.f};

  for (int kt = 0; kt < K; kt += 64) {
    __syncthreads();
#pragma unroll
    for (int c = 0; c < 4; ++c) {
      int o = ((wave * 4 + c) << 10) + (lane << 4);
      int row = o >> 7;
      int cb = (o & 127) ^ ((row & 7) << 4);   // pre-swizzled source (rule 21)
      int grow = tile_m + row; if (grow >= M) grow = M - 1;
      load_lds16(A + (size_t)grow * lda + kt + (cb >> 1),
                 (char*)ldsA + ((wave * 4 + c) << 10));
      int gcol = tile_n + row;
      load_lds16(Bm + (size_t)gcol * K + kt + (cb >> 1),
                 (char*)ldsB + ((wave * 4 + c) << 10));
    }
    __syncthreads();
#pragma unroll
    for (int kk = 0; kk < 2; ++kk) {
      short8 af[4], bfr[4];
      int kb = (kk << 6) + (lgrp << 4);
#pragma unroll
      for (int a = 0; a < 4; ++a) {
        int r = (wm << 6) + (a << 4) + lrow;
        af[a] = *(const short8*)((const char*)ldsA + (r << 7) + (kb ^ ((r & 7) << 4)));
        int rn = (wn << 6) + (a << 4) + lrow;
        bfr[a] = *(const short8*)((const char*)ldsB + (rn << 7) + (kb ^ ((rn & 7) << 4)));
      }
#pragma unroll
      for (int a = 0; a < 4; ++a)
#pragma unroll
        for (int b = 0; b < 4; ++b)
          acc[a][b] = __builtin_amdgcn_mfma_f32_16x16x32_bf16(af[a], bfr[b], acc[a][b], 0, 0, 0);
    }
  }
#pragma unroll
  for (int a = 0; a < 4; ++a)
#pragma unroll
    for (int b = 0; b < 4; ++b)
#pragma unroll
      for (int q = 0; q < 4; ++q) {
        int r = tile_m + (wm << 6) + (a << 4) + lgrp * 4 + q;   // m89 C layout
        int cc = tile_n + (wn << 6) + (b << 4) + lrow;
        if (r < M) {
          float v = acc[a][b][q];
          if (bias) v += bias[cc];
          if (OUT_F32) ((float*)Cv)[(size_t)r * ldc + cc] = v;
          else         ((short*)Cv)[(size_t)r * ldc + cc] = f2bf(v);
        }
      }
}

// ---------------- persistent recurrence (single chain, 64 fat blocks) ----------------
// Block j owns cols 16j..16j+15 of ALL gates for ALL 64 batch rows.
// hp/rhp: bf16 [prod j][row64][col16], 2KB/producer. flags: [j*16]=flagA,
// [1024+j*16]=flagB, each on its own 64B line.
// Wave w = k-quarter [256w,256w+256); consumer frag (rt,t8): producer
//   j0=16w+2*t8+(lgrp>>1), elems at j0*1024 + (rt*16+lrow)*16 + (lgrp&1)*8.
// Epilogue: wave w owns row-tile w; lane -> (row16=lane>>2, cols (lane&3)*4..+3);
//   one atomic_swap_x2 per lane. red[mat][writer wave][rt][lane*5+q].

__launch_bounds__(256, 1)
__global__ void recurrence_kernel(const short* __restrict__ pk,
                                  const short* __restrict__ Gcat,
                                  const float* __restrict__ hf,
                                  short* __restrict__ hp,
                                  short* __restrict__ rhp,
                                  uint32_t* __restrict__ flags,
                                  float* __restrict__ out) {
  __shared__ float red[3][4][4][320];   // 61.4 KB; [r/z/i][writer wave][rt][lane*5+q]
  const int j = blockIdx.x;             // 0..63
  const int tid = threadIdx.x;
  const int wave = tid >> 6;
  const int lane = tid & 63;
  const int lrow = lane & 15;
  const int lgrp = lane >> 4;

  // resident weights: per wave k-quarter, 8 frags per matrix (packing unchanged)
  short8 wr[8], wz[8], wi[8];
  {
    const short8* p8 = (const short8*)pk;
    size_t base = ((size_t)j * 4 + wave) * 8;
#pragma unroll
    for (int t8 = 0; t8 < 8; ++t8) wr[t8] = p8[(base + t8) * 64 + lane];
#pragma unroll
    for (int t8 = 0; t8 < 8; ++t8) wz[t8] = p8[((size_t)2048 + base + t8) * 64 + lane];
#pragma unroll
    for (int t8 = 0; t8 < 8; ++t8) wi[t8] = p8[((size_t)4096 + base + t8) * 64 + lane];
  }

  // epilogue assignment: wave owns row-tile `wave`; lane -> (row16, 4 cols)
  const int row16 = lane >> 2;
  const int c4 = (lane & 3) << 2;
  const int erow = wave * 16 + row16;            // 0..63
  float hold[4], zv[4];
#pragma unroll
  for (int c = 0; c < 4; ++c)
    hold[c] = hf[(size_t)erow * 1024 + (j << 4) + c4 + c];

  // consumer fragment base (elements); frag(rt,t8) at cbase0 + t8*2048 + rt*256
  const int jbase = 16 * wave + (lgrp >> 1);
  const int cbase0 = jbase * 1024 + lrow * 16 + ((lgrp & 1) << 3);
  const short* hpc  = hp  + cbase0;
  const short* rhpc = rhp + cbase0;

  // producer store addresses
  short* const prodRh = rhp + j * 1024 + erow * 16 + c4;
  short* const prodH  = hp  + j * 1024 + erow * 16 + c4;

  // Gcat gate inputs for this wave's rows (t=0 preamble, plain loads)
  float gz[4], gr[4], gi[4];
  const unsigned short* GcatU = (const unsigned short*)Gcat;
  {
    size_t rbase = ((size_t)erow * S_) * 3072 + (j << 4) + c4;
    u16x4 vz = *(const u16x4*)(GcatU + rbase);
    u16x4 vr = *(const u16x4*)(GcatU + rbase + 1024);
    u16x4 vi = *(const u16x4*)(GcatU + rbase + 2048);
#pragma unroll
    for (int c = 0; c < 4; ++c) {
      gz[c] = bf2f((short)vz[c]); gr[c] = bf2f((short)vr[c]); gi[c] = bf2f((short)vi[c]);
    }
  }

  for (int t = 0; t < S_; ++t) {
    // ---- phase 1: gate on this wave's 16 h-producers (flagB of t-1) ----
    if (t > 0) poll16(flags + 1024 + (wave << 8), (uint32_t)t);
    short8 fa[8], fb[8];
    f32x4 accr0 = (f32x4){0,0,0,0}, accr1 = accr0, accr2 = accr0, accr3 = accr0;
    f32x4 accz0 = accr0, accz1 = accr0, accz2 = accr0, accz3 = accr0;
    ISSUE8(fa, hpc, 0);          // rt0
    ISSUE8(fb, hpc, 256);        // rt1
    WAITV(8);
    MFMA_RZ(fa, accr0, accz0);
    ISSUE8(fa, hpc, 512);        // rt2
    WAITV(8);
    MFMA_RZ(fb, accr1, accz1);
    ISSUE8(fb, hpc, 768);        // rt3
    WAITV(8);
    MFMA_RZ(fa, accr2, accz2);
    WAITV(0);
    MFMA_RZ(fb, accr3, accz3);
#pragma unroll
    for (int q = 0; q < 4; ++q) {
      red[0][wave][0][lane * 5 + q] = accr0[q]; red[1][wave][0][lane * 5 + q] = accz0[q];
      red[0][wave][1][lane * 5 + q] = accr1[q]; red[1][wave][1][lane * 5 + q] = accz1[q];
      red[0][wave][2][lane * 5 + q] = accr2[q]; red[1][wave][2][lane * 5 + q] = accz2[q];
      red[0][wave][3][lane * 5 + q] = accr3[q]; red[1][wave][3][lane * 5 + q] = accz3[q];
    }
    barrier_lds();                                    // B2
    // epilogue 1 (all waves in parallel; this wave reads rt = wave)
    {
      uint32_t packed[2] = {0u, 0u};
#pragma unroll
      for (int c = 0; c < 4; ++c) {
        int li = (((row16 >> 2) << 4) + c4 + c) * 5 + (row16 & 3);
        float sr = red[0][0][wave][li] + red[0][1][wave][li] +
                   red[0][2][wave][li] + red[0][3][wave][li] + gr[c];
        float sz = red[1][0][wave][li] + red[1][1][wave][li] +
                   red[1][2][wave][li] + red[1][3][wave][li] + gz[c];
        sr = fminf(fmaxf(sr, -30.f), 30.f);
        sz = fminf(fmaxf(sz, -30.f), 30.f);
        float rv = 1.f / (1.f + __expf(-sr));
        zv[c] = 1.f / (1.f + __expf(-sz));
        packed[c >> 1] |= ((uint32_t)(uint16_t)f2bf(rv * hold[c])) << ((c & 1) * 16);
      }
      atomic_store64(prodRh, ((uint64_t)packed[1] << 32) | packed[0]);
    }
    wait_vm0();                                       // each wave's rh acked
    barrier_lds();                                    // B3: all waves acked
    if (tid == 0) atomic_store32(flags + (j << 4), (uint32_t)(t + 1));
    // issue next-step Gcat prefetch (asm; drained by phase-2 poll's vmcnt(0))
    u16x4 vzn, vrn, vin;
    {
      int tn = (t < S_ - 1) ? t + 1 : t;
      size_t rbase = ((size_t)erow * S_ + tn) * 3072 + (j << 4) + c4;
      vzn = load_g8(GcatU + rbase);
      vrn = load_g8(GcatU + rbase + 1024);
      vin = load_g8(GcatU + rbase + 2048);
    }
    // ---- phase 2: gate on this wave's 16 rh-producers (flagA of t) ----
    poll16(flags + (wave << 8), (uint32_t)(t + 1));
    f32x4 acci0 = (f32x4){0,0,0,0}, acci1 = acci0, acci2 = acci0, acci3 = acci0;
    ISSUE8(fa, rhpc, 0);         // rt0
    ISSUE8(fb, rhpc, 256);       // rt1
    WAITV(8);
    MFMA_I(fa, acci0);
    ISSUE8(fa, rhpc, 512);       // rt2
    WAITV(8);
    MFMA_I(fb, acci1);
    ISSUE8(fb, rhpc, 768);       // rt3
    WAITV(8);
    MFMA_I(fa, acci2);
    WAITV(0);
    MFMA_I(fb, acci3);
#pragma unroll
    for (int q = 0; q < 4; ++q) {
      red[2][wave][0][lane * 5 + q] = acci0[q];
      red[2][wave][1][lane * 5 + q] = acci1[q];
      red[2][wave][2][lane * 5 + q] = acci2[q];
      red[2][wave][3][lane * 5 + q] = acci3[q];
    }
    barrier_lds();                                    // B4
    // epilogue 2 (all waves in parallel)
    {
      uint32_t packed[2] = {0u, 0u};
      float hn4[4];
#pragma unroll
      for (int c = 0; c < 4; ++c) {
        int li = (((row16 >> 2) << 4) + c4 + c) * 5 + (row16 & 3);
        float si = red[2][0][wave][li] + red[2][1][wave][li] +
                   red[2][2][wave][li] + red[2][3][wave][li] + gi[c];
        si = fminf(fmaxf(si, -30.f), 30.f);
        float e2 = __expf(2.f * si);
        float hp_ = (e2 - 1.f) / (e2 + 1.f);
        float hn = (1.f - zv[c]) * hold[c] + zv[c] * hp_;
        hold[c] = hn; hn4[c] = hn;
        packed[c >> 1] |= ((uint32_t)(uint16_t)f2bf(hn)) << ((c & 1) * 16);
      }
      atomic_store64(prodH, ((uint64_t)packed[1] << 32) | packed[0]);
      if (t == S_ - 1) {
#pragma unroll
        for (int c = 0; c < 4; ++c)
          out[(size_t)erow * 1024 + (j << 4) + c4 + c] = hn4[c];
      }
    }
    wait_vm0();                                       // each wave's h acked
    barrier_lds();                                    // B5: all waves acked
    if (tid == 0) atomic_store32(flags + 1024 + (j << 4), (uint32_t)(t + 1));
    // commit prefetched gate inputs (loads drained by phase-2 poll)
#pragma unroll
    for (int c = 0; c < 4; ++c) {
      gz[c] = bf2f((short)vzn[c]); gr[c] = bf2f((short)vrn[c]); gi[c] = bf2f((short)vin[c]);
    }
  }
}

// ---------------- launch ----------------

extern "C" void kernel_launch(void* const* d_in, const int* in_sizes, int n_in,
                              void* d_out, int out_size, void* d_ws, size_t ws_size,
                              hipStream_t stream) {
  const float* x  = (const float*)d_in[0];
  const float* Wm = (const float*)d_in[1];
  const float* bm = (const float*)d_in[2];
  const float* Wh = (const float*)d_in[3];
  const float* bh = (const float*)d_in[4];
  const float* Wz = (const float*)d_in[5];
  const float* bz = (const float*)d_in[6];
  const float* Wr = (const float*)d_in[7];
  const float* br = (const float*)d_in[8];
  const float* Wi = (const float*)d_in[9];
  const float* bi = (const float*)d_in[10];

  char* ws = (char*)d_ws;
  size_t off = 0;
  auto alloc = [&](size_t bytes) -> void* {
    void* p = ws + off; off += (bytes + 255) & ~(size_t)255; return p;
  };
  short* xbf   = (short*)alloc((size_t)B_ * S_ * D_ * 2);
  short* Gcat  = (short*)alloc((size_t)B_ * S_ * 3072 * 2);
  short* Mcat  = (short*)alloc((size_t)3072 * 768 * 2);
  short* Wcat  = (short*)alloc((size_t)3072 * 1024 * 2);
  short* WmT   = (short*)alloc((size_t)768 * 1024 * 2);
  short* Whbf  = (short*)alloc((size_t)1024 * 768 * 2);
  short* pk    = (short*)alloc((size_t)3 * 1024 * 1024 * 2);   // packed r,z,i frags
  float* ccat  = (float*)alloc(3072 * 4);
  float* hf    = (float*)alloc(65536 * 4);
  short* hp    = (short*)alloc(65536 * 2);                     // packed h exchange
  short* rhp   = (short*)alloc(65536 * 2);                     // packed r*h exchange
  uint32_t* flags = (uint32_t*)alloc((size_t)2048 * 4);        // line-padded flags
  if (off > ws_size) return;

  hipMemsetAsync(flags, 0, (size_t)2048 * 4, stream);
  cast_f32_bf16_kernel<<<2048, 256, 0, stream>>>(x, xbf, (B_ * S_ * D_) / 8);
  cast_f32_bf16_kernel<<<384, 256, 0, stream>>>(Wh, Whbf, (1024 * 768) / 8);
  build_wcat_kernel<<<1536, 256, 0, stream>>>(Wz, Wr, Wi, Wcat);
  transpose_cast_kernel<<<dim3(24, 32), dim3(32, 8), 0, stream>>>(Wm, WmT);
  ccat_kernel<<<768, 256, 0, stream>>>(Wz, Wr, Wi, bm, bz, br, bi, ccat);
  pack_w_kernel<<<1536, 256, 0, stream>>>(Wz, Wr, Wi, pk);

  // Mcat[3072,768] = Wcat[3072,1024] @ WmT[768,1024]^T
  gemm_nt_kernel<false><<<dim3(24, 6), 256, 0, stream>>>(Wcat, 1024, WmT, Mcat, 768,
                                                         nullptr, 3072, 768, 1024);
  // Gcat[32768,3072] = xbf[32768,768] @ Mcat[3072,768]^T + ccat
  gemm_nt_kernel<false><<<dim3(256, 24), 256, 0, stream>>>(xbf, 768, Mcat, Gcat, 3072,
                                                           ccat, 32768, 3072, 768);
  // hf[64,1024] = x[:,0,:] @ Whbf[1024,768]^T + bh
  gemm_nt_kernel<true><<<dim3(1, 8), 256, 0, stream>>>(xbf, (long)S_ * D_, Whbf, hf, 1024,
                                                       bh, 64, 1024, 768);
  pack_h0_kernel<<<256, 256, 0, stream>>>(hf, hp);

  recurrence_kernel<<<64, 256, 0, stream>>>(pk, Gcat, hf, hp, rhp, flags,
                                            (float*)d_out);
}

// Round 13
// 2959.298 us; speedup vs baseline: 1.3293x; 1.3293x over previous
//
#include <hip/hip_runtime.h>
#include <hip/hip_bf16.h>
#include <stdint.h>

// GRU-style recurrence, B=64 S=512 D=768 H=1024.
//  REVERT to R9 (measured best: 2948us total, 2650us recurrence).
//  prep:  cast x->bf16; Wcat_u bf16 [3072,1024]; WmT bf16; Wh bf16; ccat = W*_u@bm + b*;
//         pack recurrent weights (W*[:,1024:]) into per-block MFMA B-fragments (r,z,i).
//  fold:  Mcat[3072,768] = Wcat_u @ WmT^T           (NT bf16 MFMA GEMM)
//  big:   Gcat[32768,3072] = xbf @ Mcat^T + ccat    (NT bf16 MFMA GEMM, bf16 out)
//  h0:    hf[64,1024] = x[:,0,:] @ Whbf^T + bh
//  rec:   256 blocks = 4 chains(16 rows) x 64 col-blocks. Packed 512B/producer
//         exchange blocks; atomic_swap_x2 producer stores (L3-resident); sc0sc1
//         consumer frag loads; 64B line-padded per-producer flags; per-wave
//         sliced gating; transposed epilogue via padded LDS (0 bank conflicts);
//         Gcat prefetch double-buffered on wave0.

#define B_  64
#define S_  512
#define D_  768
#define H_  1024

typedef __attribute__((ext_vector_type(8))) short short8;
typedef __attribute__((ext_vector_type(4))) float f32x4;
typedef __attribute__((ext_vector_type(4))) unsigned short u16x4;

static __device__ __forceinline__ short f2bf(float f) {
  union { float f; uint32_t u; } v; v.f = f;
  uint32_t u = v.u;
  u += 0x7FFFu + ((u >> 16) & 1u);   // RNE
  return (short)(u >> 16);
}
static __device__ __forceinline__ float bf2f(short s) {
  union { uint32_t u; float f; } v; v.u = ((uint32_t)(uint16_t)s) << 16;
  return v.f;
}
static __device__ __forceinline__ void load_lds16(const void* g, void* l) {
  __builtin_amdgcn_global_load_lds((const __attribute__((address_space(1))) void*)g,
                                   (__attribute__((address_space(3))) void*)l, 16, 0, 0);
}

// ---- exchange primitives ----
// consumer loads bypass L1/L2, read at the coherence point (L3-hit if dirty there)
static __device__ __forceinline__ short8 load_frag_sys(const short* p) {
  short8 v;
  asm volatile("global_load_dwordx4 %0, %1, off sc0 sc1" : "=v"(v) : "v"(p));
  return v;
}
// producer stores: device-scope atomics resolve in L3 (no HBM write-through, m20)
static __device__ __forceinline__ void atomic_store64(void* p, uint64_t v) {
  asm volatile("global_atomic_swap_x2 %0, %1, off" :: "v"(p), "v"(v) : "memory");
}
static __device__ __forceinline__ void atomic_store32(uint32_t* p, uint32_t v) {
  asm volatile("global_atomic_swap %0, %1, off" :: "v"(p), "v"(v) : "memory");
}
static __device__ __forceinline__ void wait_vm0() {
  asm volatile("s_waitcnt vmcnt(0)" ::: "memory");
  __builtin_amdgcn_sched_barrier(0);   // rule 18: keep consumers below the drain
}
// each WAVE polls the 16 line-padded flags of its k-quarter producers
static __device__ __forceinline__ void poll16(const uint32_t* base, uint32_t target) {
  const uint32_t* addr = base + ((threadIdx.x & 15) << 4);   // 64B-strided flags
  for (;;) {
    uint32_t v;
    asm volatile("global_load_dword %0, %1, off sc0 sc1\n\ts_waitcnt vmcnt(0)"
                 : "=v"(v) : "v"(addr) : "memory");
    if (__all((int)(v >= target))) break;
    __builtin_amdgcn_s_sleep(1);
  }
  __builtin_amdgcn_sched_barrier(0);
}

// ---------------- prep kernels ----------------

__global__ void cast_f32_bf16_kernel(const float* __restrict__ in, short* __restrict__ out, int n8) {
  int i = blockIdx.x * blockDim.x + threadIdx.x;
  int stride = gridDim.x * blockDim.x;
  for (; i < n8; i += stride) {
    const f32x4* p = (const f32x4*)(in + (size_t)i * 8);
    f32x4 a = p[0], b = p[1];
    short8 o;
    o[0] = f2bf(a[0]); o[1] = f2bf(a[1]); o[2] = f2bf(a[2]); o[3] = f2bf(a[3]);
    o[4] = f2bf(b[0]); o[5] = f2bf(b[1]); o[6] = f2bf(b[2]); o[7] = f2bf(b[3]);
    *(short8*)(out + (size_t)i * 8) = o;
  }
}

// h0 -> packed exchange layout hp[(g*64+j)*256 + row*16 + col] = h0[16g+row][16j+col]
__global__ void pack_h0_kernel(const float* __restrict__ hf, short* __restrict__ hp) {
  int i = blockIdx.x * blockDim.x + threadIdx.x;   // 65536
  int col = i & 15, row = (i >> 4) & 15, j = (i >> 8) & 63, g = i >> 14;
  hp[i] = f2bf(hf[(size_t)(16 * g + row) * 1024 + j * 16 + col]);
}

// Wcat_u bf16 [3072][1024]: rows 0..1023 = Wz[:, :1024], then Wr, then Wi
__global__ void build_wcat_kernel(const float* __restrict__ Wz, const float* __restrict__ Wr,
                                  const float* __restrict__ Wi, short* __restrict__ out) {
  int idx = blockIdx.x * blockDim.x + threadIdx.x;   // 3072*128
  int n = idx >> 7;
  int k8 = (idx & 127) << 3;
  const float* src;
  if (n < 1024)       src = Wz + ((size_t)n << 11);
  else if (n < 2048)  src = Wr + ((size_t)(n - 1024) << 11);
  else                src = Wi + ((size_t)(n - 2048) << 11);
  const f32x4* p = (const f32x4*)(src + k8);
  f32x4 a = p[0], b = p[1];
  short8 o;
  o[0] = f2bf(a[0]); o[1] = f2bf(a[1]); o[2] = f2bf(a[2]); o[3] = f2bf(a[3]);
  o[4] = f2bf(b[0]); o[5] = f2bf(b[1]); o[6] = f2bf(b[2]); o[7] = f2bf(b[3]);
  *(short8*)(out + ((size_t)n << 10) + k8) = o;
}

// WmT bf16 [768][1024], WmT[d][u] = Wm[u][d]
__global__ void transpose_cast_kernel(const float* __restrict__ in, short* __restrict__ out) {
  __shared__ float tile[32][33];
  int x = (blockIdx.x << 5) + threadIdx.x;    // d, grid.x = 24
  int y0 = (blockIdx.y << 5);                 // u, grid.y = 32
#pragma unroll
  for (int i = threadIdx.y; i < 32; i += 8)
    tile[i][threadIdx.x] = in[(size_t)(y0 + i) * 768 + x];
  __syncthreads();
  int ox = (blockIdx.y << 5) + threadIdx.x;
  int oy0 = (blockIdx.x << 5);
#pragma unroll
  for (int i = threadIdx.y; i < 32; i += 8)
    out[(size_t)(oy0 + i) * 1024 + ox] = f2bf(tile[threadIdx.x][i]);
}

// ccat[n] = sum_k W*[n_local, k<1024] * bm[k] + b*[n_local]
__global__ void ccat_kernel(const float* __restrict__ Wz, const float* __restrict__ Wr,
                            const float* __restrict__ Wi, const float* __restrict__ bm,
                            const float* __restrict__ bz, const float* __restrict__ br,
                            const float* __restrict__ bi, float* __restrict__ ccat) {
  int w = (blockIdx.x * blockDim.x + threadIdx.x) >> 6;
  int lane = threadIdx.x & 63;
  if (w >= 3072) return;
  const float* src; const float* bsrc; int ln;
  if (w < 1024)      { src = Wz + ((size_t)w << 11);          bsrc = bz; ln = w; }
  else if (w < 2048) { src = Wr + ((size_t)(w - 1024) << 11); bsrc = br; ln = w - 1024; }
  else               { src = Wi + ((size_t)(w - 2048) << 11); bsrc = bi; ln = w - 2048; }
  float acc = 0.f;
  for (int k = lane; k < 1024; k += 64) acc += src[k] * bm[k];
  for (int off = 32; off > 0; off >>= 1) acc += __shfl_down(acc, off, 64);
  if (lane == 0) ccat[w] = acc + bsrc[ln];
}

// pack recurrent weights: idx = (((m*64 + j)*4 + w)*8 + t8)*64 + lane, m: 0=r 1=z 2=i
// value = W_m[16j + (lane&15)][1024 + 256w + 32*t8 + 8*(lane>>4) + e]
__global__ void pack_w_kernel(const float* __restrict__ Wz, const float* __restrict__ Wr,
                              const float* __restrict__ Wi, short* __restrict__ out) {
  int idx = blockIdx.x * blockDim.x + threadIdx.x;   // 393216
  int lane = idx & 63;
  int t8 = (idx >> 6) & 7;
  int w = (idx >> 9) & 3;
  int j = (idx >> 11) & 63;
  int m = idx >> 17;
  int colv = (j << 4) + (lane & 15);
  int k = 1024 + (w << 8) + (t8 << 5) + ((lane >> 4) << 3);
  const float* W = (m == 0) ? Wr : (m == 1) ? Wz : Wi;
  const float* p = W + ((size_t)colv << 11) + k;
  short8 o;
#pragma unroll
  for (int e = 0; e < 8; ++e) o[e] = f2bf(p[e]);
  *(short8*)(out + ((size_t)idx << 3)) = o;
}

// ---------------- NT bf16 MFMA GEMM: C[M,N] = A[M,K] @ Bm[N,K]^T (+bias[col]) ----------------

template<bool OUT_F32>
__launch_bounds__(256, 2)
__global__ void gemm_nt_kernel(const short* __restrict__ A, long lda,
                               const short* __restrict__ Bm,
                               void* __restrict__ Cv, int ldc,
                               const float* __restrict__ bias,
                               int M, int N, int K) {
  __shared__ short ldsA[128 * 64];
  __shared__ short ldsB[128 * 64];
  const int tile_m = blockIdx.x << 7;
  const int tile_n = blockIdx.y << 7;
  const int tid = threadIdx.x;
  const int wave = tid >> 6;
  const int lane = tid & 63;
  const int wm = wave & 1;
  const int wn = wave >> 1;
  const int lrow = lane & 15;
  const int lgrp = lane >> 4;

  f32x4 acc[4][4];
#pragma unroll
  for (int a = 0; a < 4; ++a)
#pragma unroll
    for (int b = 0; b < 4; ++b) acc[a][b] = (f32x4){0.f, 0.f, 0.f, 0.f};

  for (int kt = 0; kt < K; kt += 64) {
    __syncthreads();
#pragma unroll
    for (int c = 0; c < 4; ++c) {
      int o = ((wave * 4 + c) << 10) + (lane << 4);
      int row = o >> 7;
      int cb = (o & 127) ^ ((row & 7) << 4);   // pre-swizzled source (rule 21)
      int grow = tile_m + row; if (grow >= M) grow = M - 1;
      load_lds16(A + (size_t)grow * lda + kt + (cb >> 1),
                 (char*)ldsA + ((wave * 4 + c) << 10));
      int gcol = tile_n + row;
      load_lds16(Bm + (size_t)gcol * K + kt + (cb >> 1),
                 (char*)ldsB + ((wave * 4 + c) << 10));
    }
    __syncthreads();
#pragma unroll
    for (int kk = 0; kk < 2; ++kk) {
      short8 af[4], bfr[4];
      int kb = (kk << 6) + (lgrp << 4);
#pragma unroll
      for (int a = 0; a < 4; ++a) {
        int r = (wm << 6) + (a << 4) + lrow;
        af[a] = *(const short8*)((const char*)ldsA + (r << 7) + (kb ^ ((r & 7) << 4)));
        int rn = (wn << 6) + (a << 4) + lrow;
        bfr[a] = *(const short8*)((const char*)ldsB + (rn << 7) + (kb ^ ((rn & 7) << 4)));
      }
#pragma unroll
      for (int a = 0; a < 4; ++a)
#pragma unroll
        for (int b = 0; b < 4; ++b)
          acc[a][b] = __builtin_amdgcn_mfma_f32_16x16x32_bf16(af[a], bfr[b], acc[a][b], 0, 0, 0);
    }
  }
#pragma unroll
  for (int a = 0; a < 4; ++a)
#pragma unroll
    for (int b = 0; b < 4; ++b)
#pragma unroll
      for (int q = 0; q < 4; ++q) {
        int r = tile_m + (wm << 6) + (a << 4) + lgrp * 4 + q;   // m89 C layout
        int cc = tile_n + (wn << 6) + (b << 4) + lrow;
        if (r < M) {
          float v = acc[a][b][q];
          if (bias) v += bias[cc];
          if (OUT_F32) ((float*)Cv)[(size_t)r * ldc + cc] = v;
          else         ((short*)Cv)[(size_t)r * ldc + cc] = f2bf(v);
        }
      }
}

// ---------------- persistent recurrence (packed L3-resident exchange) ----------------
// 256 blocks: g = blk>>6 (16 batch rows), j = blk&63 (cols 16j..16j+16 of ALL gates).
// hp/rhp: bf16 [(g*64+j)][row16][col16], 512B/producer. Single-buffered (WAR closure
// via B2/B4 + flags). flags per group: [j*16]=flagA, [1024+j*16]=flagB.
// Consumer wave w, frag t8: producer j0=16w+2*t8+(lgrp>>1), 16B dwordx4 at
//   (g*64+j0)*512 + lrow*32 + (lgrp&1)*16 bytes.
// Producer (wave0, transposed epilogue): lane l -> row16=l>>2, cols (l&3)*4..+3,
//   one atomic_swap_x2 (8B) at (g*64+j)*512 + row16*32 + (l&3)*8.

__launch_bounds__(256, 1)
__global__ void recurrence_kernel(const short* __restrict__ pk,
                                  const short* __restrict__ Gcat,
                                  const float* __restrict__ hf,
                                  short* __restrict__ hp,
                                  short* __restrict__ rhp,
                                  uint32_t* __restrict__ flags,
                                  float* __restrict__ out) {
  __shared__ float red[3][4][320];   // [matrix r/z/i][wave][lane*5+q] (stride 5: 2-way max)
  const int blk = blockIdx.x;
  const int g = blk >> 6;
  const int j = blk & 63;
  const int tid = threadIdx.x;
  const int wave = tid >> 6;
  const int lane = tid & 63;
  const int lrow = lane & 15;
  const int lgrp = lane >> 4;
  const int m0 = g << 4;

  // resident weights: per wave k-quarter, 8 frags per matrix
  short8 wr[8], wz[8], wi[8];
  {
    const short8* p8 = (const short8*)pk;
    size_t base = ((size_t)j * 4 + wave) * 8;
#pragma unroll
    for (int t8 = 0; t8 < 8; ++t8) wr[t8] = p8[(base + t8) * 64 + lane];
#pragma unroll
    for (int t8 = 0; t8 < 8; ++t8) wz[t8] = p8[((size_t)2048 + base + t8) * 64 + lane];
#pragma unroll
    for (int t8 = 0; t8 < 8; ++t8) wi[t8] = p8[((size_t)4096 + base + t8) * 64 + lane];
  }

  uint32_t* fgrp = flags + (g << 11);           // flagA at +0, flagB at +1024 (dwords)

  // transposed epilogue assignment (wave0): row16 = lane>>2, cols c4..c4+3
  const int row16 = lane >> 2;
  const int c4 = (lane & 3) << 2;
  float hold[4];
  float zv[4];
  if (wave == 0) {
#pragma unroll
    for (int c = 0; c < 4; ++c)
      hold[c] = hf[((size_t)(m0 + row16) << 10) + (j << 4) + c4 + c];
  }

  // consumer fragment bases (bf16 elements): per t8 add 2 producers = 512 elems
  const size_t cbase = ((size_t)(g * 64) << 8);
  const int coff = ((16 * wave + (lgrp >> 1)) << 8) + (lrow << 4) + ((lgrp & 1) << 3);

  // producer store byte address (wave0)
  short* const prodRh = rhp + ((size_t)(g * 64 + j) << 8) + (row16 << 4) + c4;
  short* const prodH  = hp  + ((size_t)(g * 64 + j) << 8) + (row16 << 4) + c4;

  // Gcat gate inputs (transposed assignment), double-buffered one step ahead
  float gz[4], gr[4], gi[4], gzn[4], grn[4], gin[4];
  const unsigned short* GcatU = (const unsigned short*)Gcat;
  if (wave == 0) {
    size_t rbase = ((size_t)(m0 + row16) * S_) * 3072 + (j << 4) + c4;   // t = 0
    u16x4 vz = *(const u16x4*)(GcatU + rbase);
    u16x4 vr = *(const u16x4*)(GcatU + rbase + 1024);
    u16x4 vi = *(const u16x4*)(GcatU + rbase + 2048);
#pragma unroll
    for (int c = 0; c < 4; ++c) {
      gz[c] = bf2f((short)vz[c]); gr[c] = bf2f((short)vr[c]); gi[c] = bf2f((short)vi[c]);
    }
  }

  for (int t = 0; t < S_; ++t) {
    // ---- phase 1: self-gated on this wave's 16 h-producers ----
    if (t > 0) poll16(fgrp + 1024 + (wave << 8), (uint32_t)t);
    short8 hfrag[8];
#pragma unroll
    for (int t8 = 0; t8 < 8; ++t8)
      hfrag[t8] = load_frag_sys(hp + cbase + coff + (t8 << 9));
    wait_vm0();
    f32x4 accr = (f32x4){0.f,0.f,0.f,0.f}, accz = (f32x4){0.f,0.f,0.f,0.f};
#pragma unroll
    for (int t8 = 0; t8 < 8; ++t8) {
      accr = __builtin_amdgcn_mfma_f32_16x16x32_bf16(hfrag[t8], wr[t8], accr, 0, 0, 0);
      accz = __builtin_amdgcn_mfma_f32_16x16x32_bf16(hfrag[t8], wz[t8], accz, 0, 0, 0);
    }
#pragma unroll
    for (int q = 0; q < 4; ++q) {
      red[0][wave][lane * 5 + q] = accr[q];
      red[1][wave][lane * 5 + q] = accz[q];
    }
    __syncthreads();                                  // B2 (joins all sliced polls)
    if (wave == 0) {
      uint32_t packed[2] = {0u, 0u};
#pragma unroll
      for (int c = 0; c < 4; ++c) {
        int li = (((row16 >> 2) << 4) + c4 + c) * 5 + (row16 & 3);
        float sr = red[0][0][li] + red[0][1][li] + red[0][2][li] + red[0][3][li] + gr[c];
        float sz = red[1][0][li] + red[1][1][li] + red[1][2][li] + red[1][3][li] + gz[c];
        sr = fminf(fmaxf(sr, -30.f), 30.f);
        sz = fminf(fmaxf(sz, -30.f), 30.f);
        float rv = 1.f / (1.f + __expf(-sr));
        zv[c] = 1.f / (1.f + __expf(-sz));
        packed[c >> 1] |= ((uint32_t)(uint16_t)f2bf(rv * hold[c])) << ((c & 1) * 16);
      }
      atomic_store64(prodRh, ((uint64_t)packed[1] << 32) | packed[0]);
      wait_vm0();                                     // release: atomic acked at L3
      if (lane == 0) atomic_store32(fgrp + (j << 4), (uint32_t)(t + 1));
      // prefetch next step's Gcat gate inputs (drains under phase-2 poll/load)
      int tn = (t < S_ - 1) ? t + 1 : t;
      size_t rbase = ((size_t)(m0 + row16) * S_ + tn) * 3072 + (j << 4) + c4;
      u16x4 vz = *(const u16x4*)(GcatU + rbase);
      u16x4 vr = *(const u16x4*)(GcatU + rbase + 1024);
      u16x4 vi = *(const u16x4*)(GcatU + rbase + 2048);
#pragma unroll
      for (int c = 0; c < 4; ++c) {
        gzn[c] = bf2f((short)vz[c]); grn[c] = bf2f((short)vr[c]); gin[c] = bf2f((short)vi[c]);
      }
    }
    // ---- phase 2: self-gated on this wave's 16 rh-producers ----
    poll16(fgrp + (wave << 8), (uint32_t)(t + 1));
    short8 rhfrag[8];
#pragma unroll
    for (int t8 = 0; t8 < 8; ++t8)
      rhfrag[t8] = load_frag_sys(rhp + cbase + coff + (t8 << 9));
    wait_vm0();
    f32x4 acci = (f32x4){0.f,0.f,0.f,0.f};
#pragma unroll
    for (int t8 = 0; t8 < 8; ++t8)
      acci = __builtin_amdgcn_mfma_f32_16x16x32_bf16(rhfrag[t8], wi[t8], acci, 0, 0, 0);
#pragma unroll
    for (int q = 0; q < 4; ++q) red[2][wave][lane * 5 + q] = acci[q];
    __syncthreads();                                  // B4 (joins all sliced polls)
    if (wave == 0) {
      uint32_t packed[2] = {0u, 0u};
      float hn4[4];
#pragma unroll
      for (int c = 0; c < 4; ++c) {
        int li = (((row16 >> 2) << 4) + c4 + c) * 5 + (row16 & 3);
        float si = red[2][0][li] + red[2][1][li] + red[2][2][li] + red[2][3][li] + gi[c];
        si = fminf(fmaxf(si, -30.f), 30.f);
        float e2 = __expf(2.f * si);
        float hp_ = (e2 - 1.f) / (e2 + 1.f);
        float hn = (1.f - zv[c]) * hold[c] + zv[c] * hp_;
        hold[c] = hn; hn4[c] = hn;
        packed[c >> 1] |= ((uint32_t)(uint16_t)f2bf(hn)) << ((c & 1) * 16);
      }
      atomic_store64(prodH, ((uint64_t)packed[1] << 32) | packed[0]);
      if (t == S_ - 1) {
#pragma unroll
        for (int c = 0; c < 4; ++c)
          out[((size_t)(m0 + row16) << 10) + (j << 4) + c4 + c] = hn4[c];
      }
      wait_vm0();                                     // release
      if (lane == 0) atomic_store32(fgrp + 1024 + (j << 4), (uint32_t)(t + 1));
#pragma unroll
      for (int c = 0; c < 4; ++c) { gz[c] = gzn[c]; gr[c] = grn[c]; gi[c] = gin[c]; }
    }
  }
}

// ---------------- launch ----------------

extern "C" void kernel_launch(void* const* d_in, const int* in_sizes, int n_in,
                              void* d_out, int out_size, void* d_ws, size_t ws_size,
                              hipStream_t stream) {
  const float* x  = (const float*)d_in[0];
  const float* Wm = (const float*)d_in[1];
  const float* bm = (const float*)d_in[2];
  const float* Wh = (const float*)d_in[3];
  const float* bh = (const float*)d_in[4];
  const float* Wz = (const float*)d_in[5];
  const float* bz = (const float*)d_in[6];
  const float* Wr = (const float*)d_in[7];
  const float* br = (const float*)d_in[8];
  const float* Wi = (const float*)d_in[9];
  const float* bi = (const float*)d_in[10];

  char* ws = (char*)d_ws;
  size_t off = 0;
  auto alloc = [&](size_t bytes) -> void* {
    void* p = ws + off; off += (bytes + 255) & ~(size_t)255; return p;
  };
  short* xbf   = (short*)alloc((size_t)B_ * S_ * D_ * 2);
  short* Gcat  = (short*)alloc((size_t)B_ * S_ * 3072 * 2);
  short* Mcat  = (short*)alloc((size_t)3072 * 768 * 2);
  short* Wcat  = (short*)alloc((size_t)3072 * 1024 * 2);
  short* WmT   = (short*)alloc((size_t)768 * 1024 * 2);
  short* Whbf  = (short*)alloc((size_t)1024 * 768 * 2);
  short* pk    = (short*)alloc((size_t)3 * 1024 * 1024 * 2);   // packed r,z,i frags
  float* ccat  = (float*)alloc(3072 * 4);
  float* hf    = (float*)alloc(65536 * 4);
  short* hp    = (short*)alloc(65536 * 2);                     // packed h exchange
  short* rhp   = (short*)alloc(65536 * 2);                     // packed r*h exchange
  uint32_t* flags = (uint32_t*)alloc((size_t)4 * 2048 * 4);    // line-padded flags
  if (off > ws_size) return;

  hipMemsetAsync(flags, 0, (size_t)4 * 2048 * 4, stream);
  cast_f32_bf16_kernel<<<2048, 256, 0, stream>>>(x, xbf, (B_ * S_ * D_) / 8);
  cast_f32_bf16_kernel<<<384, 256, 0, stream>>>(Wh, Whbf, (1024 * 768) / 8);
  build_wcat_kernel<<<1536, 256, 0, stream>>>(Wz, Wr, Wi, Wcat);
  transpose_cast_kernel<<<dim3(24, 32), dim3(32, 8), 0, stream>>>(Wm, WmT);
  ccat_kernel<<<768, 256, 0, stream>>>(Wz, Wr, Wi, bm, bz, br, bi, ccat);
  pack_w_kernel<<<1536, 256, 0, stream>>>(Wz, Wr, Wi, pk);

  // Mcat[3072,768] = Wcat[3072,1024] @ WmT[768,1024]^T
  gemm_nt_kernel<false><<<dim3(24, 6), 256, 0, stream>>>(Wcat, 1024, WmT, Mcat, 768,
                                                         nullptr, 3072, 768, 1024);
  // Gcat[32768,3072] = xbf[32768,768] @ Mcat[3072,768]^T + ccat
  gemm_nt_kernel<false><<<dim3(256, 24), 256, 0, stream>>>(xbf, 768, Mcat, Gcat, 3072,
                                                           ccat, 32768, 3072, 768);
  // hf[64,1024] = x[:,0,:] @ Whbf[1024,768]^T + bh
  gemm_nt_kernel<true><<<dim3(1, 8), 256, 0, stream>>>(xbf, (long)S_ * D_, Whbf, hf, 1024,
                                                       bh, 64, 1024, 768);
  pack_h0_kernel<<<256, 256, 0, stream>>>(hf, hp);

  recurrence_kernel<<<256, 256, 0, stream>>>(pk, Gcat, hf, hp, rhp, flags,
                                             (float*)d_out);
}